// Round 1
// baseline (108.980 us; speedup 1.0000x reference)
//
#include <hip/hip_runtime.h>
#include <hip/hip_bf16.h>

#define F 64
#define C 128
#define M_BLK 128
#define XSTRIDE 80  // bf16 elems per LDS row: 64 + 16 pad (keeps 16B align, spreads banks)

typedef __attribute__((ext_vector_type(8))) short short8;
typedef __attribute__((ext_vector_type(4))) float floatx4;
typedef __attribute__((ext_vector_type(4))) unsigned short ushort4_t;

__device__ __forceinline__ unsigned short f32_to_bf16_rne(float f) {
    unsigned int u = __builtin_bit_cast(unsigned int, f);
    unsigned int r = u + 0x7FFFu + ((u >> 16) & 1u);
    return (unsigned short)(r >> 16);
}

__device__ __forceinline__ float sigmoidf(float v) {
    return 1.0f / (1.0f + __expf(-v));
}

__global__ __launch_bounds__(256) void fused_seg_gemm(
    const float* __restrict__ x, const float* __restrict__ w,
    const int* __restrict__ seg, float* __restrict__ out)
{
    __shared__ float wlds[F * C];                      // 32 KB fp32 W as-is
    __shared__ unsigned short xlds[M_BLK * XSTRIDE];   // 20 KB bf16 X tile
    __shared__ int seg_lds[M_BLK];

    const int tid  = threadIdx.x;
    const int lane = tid & 63;
    const int wave = tid >> 6;
    const long long row0 = (long long)blockIdx.x * M_BLK;

    // ---- stage W: 8192 f32 = 2048 float4, coalesced ----
    {
        const float4* wsrc = (const float4*)w;
        float4* wdst = (float4*)wlds;
        #pragma unroll
        for (int i = 0; i < 8; ++i) wdst[tid + i * 256] = wsrc[tid + i * 256];
    }
    // ---- stage X: 128 rows x 16 float4, convert fp32->bf16 ----
    {
        const float4* xsrc = (const float4*)(x + row0 * F);
        #pragma unroll
        for (int p = 0; p < 8; ++p) {
            int linear = tid + p * 256;
            int item = linear >> 4;
            int kq   = linear & 15;
            float4 v = xsrc[linear];
            ushort4_t b;
            b.x = f32_to_bf16_rne(v.x); b.y = f32_to_bf16_rne(v.y);
            b.z = f32_to_bf16_rne(v.z); b.w = f32_to_bf16_rne(v.w);
            *(ushort4_t*)(&xlds[item * XSTRIDE + kq * 4]) = b;
        }
    }
    if (tid < M_BLK) seg_lds[tid] = seg[row0 + tid];
    __syncthreads();

    // ---- build B fragments from LDS W (once per block) ----
    // frag convention: operand M/N index = lane&15, k = ks*32 + (lane>>4)*8 + e
    short8 bfrag[2][2];
    {
        const int kg = (lane >> 4) * 8;
        #pragma unroll
        for (int nf = 0; nf < 2; ++nf) {
            const int col = wave * 32 + nf * 16 + (lane & 15);
            #pragma unroll
            for (int ks = 0; ks < 2; ++ks) {
                short8 t;
                #pragma unroll
                for (int e = 0; e < 8; ++e) {
                    int k = ks * 32 + kg + e;
                    t[e] = (short)f32_to_bf16_rne(wlds[k * C + col]);
                }
                bfrag[nf][ks] = t;
            }
        }
    }

    floatx4 acc[8][2];
    #pragma unroll
    for (int mf = 0; mf < 8; ++mf)
        #pragma unroll
        for (int nf = 0; nf < 2; ++nf) acc[mf][nf] = (floatx4)0.0f;

    // ---- MFMA main: wave = 128 items x 32 cols, K=64 ----
    #pragma unroll
    for (int mf = 0; mf < 8; ++mf) {
        const int row = mf * 16 + (lane & 15);
        const int k0  = (lane >> 4) * 8;
        #pragma unroll
        for (int ks = 0; ks < 2; ++ks) {
            short8 a = *(const short8*)(&xlds[row * XSTRIDE + ks * 32 + k0]);
            #pragma unroll
            for (int nf = 0; nf < 2; ++nf)
                acc[mf][nf] = __builtin_amdgcn_mfma_f32_16x16x32_bf16(
                    a, bfrag[nf][ks], acc[mf][nf], 0, 0, 0);
        }
    }

    // ---- sigmoid + segmented reduce ----
    // C/D layout (m89-verified): col = lane&15, row(frag) = (lane>>4)*4 + reg
    const int seg_first = seg_lds[0];
    const bool uniform = (seg_first == seg_lds[M_BLK - 1]);
    const int colb = wave * 32;

    if (uniform) {
        float s0 = 0.0f, s1 = 0.0f;
        #pragma unroll
        for (int mf = 0; mf < 8; ++mf)
            #pragma unroll
            for (int r = 0; r < 4; ++r) {
                s0 += sigmoidf(acc[mf][0][r]);
                s1 += sigmoidf(acc[mf][1][r]);
            }
        s0 += __shfl_xor(s0, 16); s0 += __shfl_xor(s0, 32);
        s1 += __shfl_xor(s1, 16); s1 += __shfl_xor(s1, 32);
        if (lane < 16)      atomicAdd(&out[seg_first * C + colb + lane], s0);
        else if (lane < 32) atomicAdd(&out[seg_first * C + colb + 16 + (lane & 15)], s1);
    } else {
        const int g = lane >> 4;
        #pragma unroll
        for (int nf = 0; nf < 2; ++nf) {
            const int col = colb + nf * 16 + (lane & 15);
            int   cur_seg = seg_lds[g * 4];
            float cur = 0.0f;
            #pragma unroll
            for (int mf = 0; mf < 8; ++mf)
                #pragma unroll
                for (int r = 0; r < 4; ++r) {
                    int row = mf * 16 + g * 4 + r;   // monotone increasing walk
                    int sg  = seg_lds[row];
                    float v = sigmoidf(acc[mf][nf][r]);
                    if (sg != cur_seg) {
                        atomicAdd(&out[cur_seg * C + col], cur);
                        cur_seg = sg; cur = v;
                    } else {
                        cur += v;
                    }
                }
            atomicAdd(&out[cur_seg * C + col], cur);
        }
    }
}

extern "C" void kernel_launch(void* const* d_in, const int* in_sizes, int n_in,
                              void* d_out, int out_size, void* d_ws, size_t ws_size,
                              hipStream_t stream) {
    const float* x  = (const float*)d_in[0];
    const float* w  = (const float*)d_in[1];
    const int* seg  = (const int*)d_in[2];
    float* out      = (float*)d_out;

    const int n = in_sizes[0] / F;          // 1048576
    const int nblocks = n / M_BLK;          // 8192

    // harness poisons d_out with 0xAA and never re-poisons between replays:
    // we must zero it every call (memset is graph-capturable on-stream)
    hipMemsetAsync(d_out, 0, (size_t)out_size * sizeof(float), stream);

    fused_seg_gemm<<<nblocks, 256, 0, stream>>>(x, w, seg, out);
}

// Round 2
// 89.803 us; speedup vs baseline: 1.2135x; 1.2135x over previous
//
#include <hip/hip_runtime.h>
#include <hip/hip_bf16.h>

#define F 64
#define C 128
#define M_BLK 128
#define XSTRIDE 72  // ushorts per LDS row = 144 B: 2-way bank aliasing only (free), 16B-aligned

typedef __attribute__((ext_vector_type(8))) short short8;
typedef __attribute__((ext_vector_type(4))) float floatx4;
typedef __attribute__((ext_vector_type(4))) unsigned short ushort4_t;

__device__ __forceinline__ unsigned short f32_to_bf16_rne(float f) {
    unsigned int u = __builtin_bit_cast(unsigned int, f);
    unsigned int r = u + 0x7FFFu + ((u >> 16) & 1u);
    return (unsigned short)(r >> 16);
}

__device__ __forceinline__ float sigmoidf(float v) {
    return 1.0f / (1.0f + __expf(-v));
}

// One dispatch: zero d_out (blocks 0..Z-1) and build per-lane bf16 W-fragments
// into d_ws (last block). Frag entry idx = ((wave*2+nf)*2+ks)*64+lane, 16 B each.
__global__ __launch_bounds__(256) void prep_kernel(
    const float* __restrict__ w, float* __restrict__ out,
    unsigned short* __restrict__ wsfrag, int out_f4)
{
    const int b = blockIdx.x;
    if (b < (int)gridDim.x - 1) {
        int idx = b * 256 + threadIdx.x;
        if (idx < out_f4) ((float4*)out)[idx] = make_float4(0.f, 0.f, 0.f, 0.f);
    } else {
        #pragma unroll
        for (int i = 0; i < 4; ++i) {
            int idx = threadIdx.x * 4 + i;           // 0..1023
            int lane = idx & 63;
            int ks   = (idx >> 6) & 1;
            int nf   = (idx >> 7) & 1;
            int wv   = idx >> 8;
            int col  = wv * 32 + nf * 16 + (lane & 15);
            int kg   = (lane >> 4) * 8;
            unsigned short* dst = wsfrag + (size_t)idx * 8;
            #pragma unroll
            for (int e = 0; e < 8; ++e) {
                int k = ks * 32 + kg + e;
                dst[e] = f32_to_bf16_rne(w[k * C + col]);
            }
        }
    }
}

__global__ __launch_bounds__(256, 4) void fused_seg_gemm(
    const float* __restrict__ x, const unsigned short* __restrict__ wsfrag,
    const int* __restrict__ seg, float* __restrict__ out)
{
    __shared__ unsigned short xlds[M_BLK * XSTRIDE];   // 18 KB bf16 X tile
    __shared__ int seg_lds[M_BLK];

    const int tid  = threadIdx.x;
    const int lane = tid & 63;
    const int wave = tid >> 6;
    const long long row0 = (long long)blockIdx.x * M_BLK;

    if (tid < M_BLK) seg_lds[tid] = seg[row0 + tid];

    // ---- B fragments: 4 coalesced dwordx4 from L2-resident ws ----
    short8 bfrag[2][2];
    {
        const short8* fb = (const short8*)wsfrag;
        #pragma unroll
        for (int nf = 0; nf < 2; ++nf)
            #pragma unroll
            for (int ks = 0; ks < 2; ++ks)
                bfrag[nf][ks] = fb[((wave * 2 + nf) * 2 + ks) * 64 + lane];
    }

    // ---- stage X: 128 rows x 16 float4, convert fp32->bf16 in regs ----
    {
        const float4* xsrc = (const float4*)(x + row0 * F);
        #pragma unroll
        for (int p = 0; p < 8; ++p) {
            int linear = tid + p * 256;
            int item = linear >> 4;
            int kq   = linear & 15;
            float4 v = xsrc[linear];
            ushort4_t bv;
            bv.x = f32_to_bf16_rne(v.x); bv.y = f32_to_bf16_rne(v.y);
            bv.z = f32_to_bf16_rne(v.z); bv.w = f32_to_bf16_rne(v.w);
            *(ushort4_t*)(&xlds[item * XSTRIDE + kq * 4]) = bv;
        }
    }
    __syncthreads();

    floatx4 acc[8][2];
    #pragma unroll
    for (int mf = 0; mf < 8; ++mf)
        #pragma unroll
        for (int nf = 0; nf < 2; ++nf) acc[mf][nf] = (floatx4)0.0f;

    // ---- MFMA main: wave = 128 items x 32 cols, K=64 ----
    #pragma unroll
    for (int mf = 0; mf < 8; ++mf) {
        const int row = mf * 16 + (lane & 15);
        const int k0  = (lane >> 4) * 8;
        #pragma unroll
        for (int ks = 0; ks < 2; ++ks) {
            short8 a = *(const short8*)(&xlds[row * XSTRIDE + ks * 32 + k0]);
            #pragma unroll
            for (int nf = 0; nf < 2; ++nf)
                acc[mf][nf] = __builtin_amdgcn_mfma_f32_16x16x32_bf16(
                    a, bfrag[nf][ks], acc[mf][nf], 0, 0, 0);
        }
    }

    // ---- sigmoid + segmented reduce ----
    // C/D layout (m89): col = lane&15, frag row = (lane>>4)*4 + reg
    const int seg_first = seg_lds[0];
    const bool uniform = (seg_first == seg_lds[M_BLK - 1]);
    const int colb = wave * 32;

    if (uniform) {
        float s0 = 0.0f, s1 = 0.0f;
        #pragma unroll
        for (int mf = 0; mf < 8; ++mf)
            #pragma unroll
            for (int r = 0; r < 4; ++r) {
                s0 += sigmoidf(acc[mf][0][r]);
                s1 += sigmoidf(acc[mf][1][r]);
            }
        s0 += __shfl_xor(s0, 16); s0 += __shfl_xor(s0, 32);
        s1 += __shfl_xor(s1, 16); s1 += __shfl_xor(s1, 32);
        if (lane < 16)      atomicAdd(&out[seg_first * C + colb + lane], s0);
        else if (lane < 32) atomicAdd(&out[seg_first * C + colb + 16 + (lane & 15)], s1);
    } else {
        const int g = lane >> 4;
        #pragma unroll
        for (int nf = 0; nf < 2; ++nf) {
            const int col = colb + nf * 16 + (lane & 15);
            int   cur_seg = seg_lds[g * 4];
            float cur = 0.0f;
            #pragma unroll
            for (int mf = 0; mf < 8; ++mf)
                #pragma unroll
                for (int r = 0; r < 4; ++r) {
                    int row = mf * 16 + g * 4 + r;   // monotone increasing walk
                    int sg  = seg_lds[row];
                    float v = sigmoidf(acc[mf][nf][r]);
                    if (sg != cur_seg) {
                        atomicAdd(&out[cur_seg * C + col], cur);
                        cur_seg = sg; cur = v;
                    } else {
                        cur += v;
                    }
                }
            atomicAdd(&out[cur_seg * C + col], cur);
        }
    }
}

extern "C" void kernel_launch(void* const* d_in, const int* in_sizes, int n_in,
                              void* d_out, int out_size, void* d_ws, size_t ws_size,
                              hipStream_t stream) {
    const float* x  = (const float*)d_in[0];
    const float* w  = (const float*)d_in[1];
    const int* seg  = (const int*)d_in[2];
    float* out      = (float*)d_out;

    const int n = in_sizes[0] / F;          // 1048576
    const int nblocks = n / M_BLK;          // 8192

    const int out_f4 = out_size / 4;        // float4 count (out_size divisible by 4)
    const int zblocks = (out_f4 + 255) / 256;

    // zero d_out + rebuild W frags every call (ws/out are poisoned once by harness)
    prep_kernel<<<zblocks + 1, 256, 0, stream>>>(
        w, out, (unsigned short*)d_ws, out_f4);

    fused_seg_gemm<<<nblocks, 256, 0, stream>>>(
        x, (const unsigned short*)d_ws, seg, out);
}